// Round 3
// baseline (168.887 us; speedup 1.0000x reference)
//
#include <hip/hip_runtime.h>
#include <stdint.h>

typedef __attribute__((ext_vector_type(8))) short bf8v;   // 8 bf16 raw bits (4 VGPRs)
typedef __attribute__((ext_vector_type(4))) float f4v;
typedef __attribute__((ext_vector_type(16))) float f16v;
typedef __attribute__((ext_vector_type(4))) unsigned int u4v;

__device__ __forceinline__ unsigned short f2bf(float f) {
  unsigned int u = __float_as_uint(f);
  u += 0x7fffu + ((u >> 16) & 1u);   // round-to-nearest-even
  return (unsigned short)(u >> 16);
}

__device__ __forceinline__ void gload16(const void* g, void* l) {
  __builtin_amdgcn_global_load_lds(
      (__attribute__((address_space(1))) void*)reinterpret_cast<uintptr_t>(g),
      (__attribute__((address_space(3))) void*)reinterpret_cast<uintptr_t>(l),
      16, 0, 0);
}

__device__ __forceinline__ unsigned cvtpk(float lo, float hi) {
  unsigned r;
  asm("v_cvt_pk_bf16_f32 %0, %1, %2" : "=v"(r) : "v"(lo), "v"(hi));
  return r;
}

// ---------------- fp32 -> bf16 conversion (single fused launch) ----------------
// layout: 3 activation tensors of NA=4M elems, then 4 weight tensors of NW=1M.
__global__ __launch_bounds__(256) void cvt_all(
    const float* __restrict__ s0, const float* __restrict__ s1,
    const float* __restrict__ s2, const float* __restrict__ s3,
    const float* __restrict__ s4, const float* __restrict__ s5,
    const float* __restrict__ s6, unsigned short* __restrict__ dst) {
  const size_t NA = (size_t)1 << 22, NW = (size_t)1 << 20;
  size_t i = ((size_t)blockIdx.x * 256 + threadIdx.x) * 8;
  const float* src;
  size_t off;
  if (i < 3 * NA) {
    int a = (int)(i >> 22);
    src = (a == 0) ? s0 : (a == 1) ? s1 : s2;
    off = i & (NA - 1);
  } else {
    size_t j = i - 3 * NA;
    int a = (int)(j >> 20);
    src = (a == 0) ? s3 : (a == 1) ? s4 : (a == 2) ? s5 : s6;
    off = j & (NW - 1);
  }
  const f4v* sp = (const f4v*)(src + off);
  f4v x = sp[0], y = sp[1];
  bf8v r;
  r[0] = (short)f2bf(x[0]); r[1] = (short)f2bf(x[1]);
  r[2] = (short)f2bf(x[2]); r[3] = (short)f2bf(x[3]);
  r[4] = (short)f2bf(y[0]); r[5] = (short)f2bf(y[1]);
  r[6] = (short)f2bf(y[2]); r[7] = (short)f2bf(y[3]);
  *(bf8v*)(dst + i) = r;
}

// ---------------- 128x128x(BK=32) bf16 GEMM body (m97 structure) ----------------
template <int OMODE>
__device__ __forceinline__ void gemm_body(
    unsigned short* Al, unsigned short* Bl,
    const unsigned short* __restrict__ A, const unsigned short* __restrict__ W,
    const float* __restrict__ bias, void* __restrict__ out) {
  const int tid = threadIdx.x;
  const int w = tid >> 6, l = tid & 63;
  const int lr = l >> 4, lc = l & 15;
  const int m0 = blockIdx.x * 128, n0 = blockIdx.y * 128;
  const int wr = w >> 1, wc = w & 1;

  f4v acc[4][4];
#pragma unroll
  for (int i = 0; i < 4; i++)
#pragma unroll
    for (int j = 0; j < 4; j++) acc[i][j] = (f4v)(0.0f);

  const int NK = 32;
#pragma unroll
  for (int i = 0; i < 2; i++) {
    int chunk = w * 2 + i;
    int e = (chunk * 1024 + l * 16) >> 1;
    int r = e >> 5, k = e & 31;
    gload16(A + (size_t)(m0 + r) * 1024 + k, Al + chunk * 512);
    gload16(W + (size_t)(n0 + r) * 1024 + k, Bl + chunk * 512);
  }

  for (int kk = 0; kk < NK; kk++) {
    const int cur = kk & 1;
    __syncthreads();
    if (kk + 1 < NK) {
#pragma unroll
      for (int i = 0; i < 2; i++) {
        int chunk = w * 2 + i;
        int e = (chunk * 1024 + l * 16) >> 1;
        int r = e >> 5, k = (kk + 1) * 32 + (e & 31);
        gload16(A + (size_t)(m0 + r) * 1024 + k, Al + (cur ^ 1) * 4096 + chunk * 512);
        gload16(W + (size_t)(n0 + r) * 1024 + k, Bl + (cur ^ 1) * 4096 + chunk * 512);
      }
    }
    bf8v av[4], bv[4];
#pragma unroll
    for (int i = 0; i < 4; i++) {
      int row = wr * 64 + i * 16 + lc;
      av[i] = *(const bf8v*)(Al + cur * 4096 + row * 32 + lr * 8);
    }
#pragma unroll
    for (int j = 0; j < 4; j++) {
      int row = wc * 64 + j * 16 + lc;
      bv[j] = *(const bf8v*)(Bl + cur * 4096 + row * 32 + lr * 8);
    }
#pragma unroll
    for (int i = 0; i < 4; i++)
#pragma unroll
      for (int j = 0; j < 4; j++)
        acc[i][j] = __builtin_amdgcn_mfma_f32_16x16x32_bf16(av[i], bv[j], acc[i][j], 0, 0, 0);
  }

#pragma unroll
  for (int j = 0; j < 4; j++) {
    int n = n0 + wc * 64 + j * 16 + lc;
    float bj = bias[n];
#pragma unroll
    for (int i = 0; i < 4; i++) {
      int mb = m0 + wr * 64 + i * 16 + lr * 4;
#pragma unroll
      for (int q = 0; q < 4; q++) {
        float val = fmaxf(acc[i][j][q] + bj, 0.0f);
        int m = mb + q;
        if (OMODE == 2) {
          int s = m & 2047, b = m >> 11;
          ((float*)out)[(size_t)(s * 2 + b) * 1024 + n] = val;
        } else {
          int s = m >> 1, b = m & 1;
          int h = n >> 6, d = n & 63;
          if (OMODE == 0)
            ((unsigned short*)out)[((size_t)(b * 16 + h) * 2048 + s) * 64 + d] = f2bf(val);
          else
            ((unsigned short*)out)[((size_t)(b * 16 + h) * 64 + d) * 2048 + s] = f2bf(val);
        }
      }
    }
  }
}

__global__ __launch_bounds__(256) void qkv_gemm(
    const unsigned short* __restrict__ qA, const unsigned short* __restrict__ kA,
    const unsigned short* __restrict__ vA,
    const unsigned short* __restrict__ Wq, const unsigned short* __restrict__ Wk,
    const unsigned short* __restrict__ Wv,
    const float* __restrict__ bq, const float* __restrict__ bk,
    const float* __restrict__ bv,
    unsigned short* __restrict__ Qh, unsigned short* __restrict__ Kh,
    unsigned short* __restrict__ Vt) {
  __shared__ __align__(16) unsigned short Al[2 * 4096];
  __shared__ __align__(16) unsigned short Bl[2 * 4096];
  int z = blockIdx.z;
  if (z == 0)      gemm_body<0>(Al, Bl, qA, Wq, bq, Qh);
  else if (z == 1) gemm_body<0>(Al, Bl, kA, Wk, bk, Kh);
  else             gemm_body<1>(Al, Bl, vA, Wv, bv, Vt);
}

__global__ __launch_bounds__(256) void out_gemm(
    const unsigned short* __restrict__ Y, const unsigned short* __restrict__ Wo,
    const float* __restrict__ bo, float* __restrict__ out) {
  __shared__ __align__(16) unsigned short Al[2 * 4096];
  __shared__ __align__(16) unsigned short Bl[2 * 4096];
  gemm_body<2>(Al, Bl, Y, Wo, bo, out);
}

// ---------------- flash attention, 32x32 swapped, register-direct ----------------
// Qh,Kh: (BH=32, S=2048, 64) bf16.  Vt: (BH, 64, S) bf16.  Y: (B,S,D) bf16.
// Grid (32 qtiles, 32 bh), 64 threads = 1 wave, NO LDS, NO barriers.
// K/V are L2-resident per bh (512 KB); fragments load global->reg, double-
// buffered one 32-kv chunk ahead (static A/B phases, rule #20).
// QK^T: S^T[kv][q] = mfma(Kfrag, Qfrag) -> lane holds 16 p for q=lane&31.
// Softmax in-lane + shfl_xor(32); T12 cvt_pk+permlane32_swap; T13 defer-max.
// PV: O^T[d][q] = mfma(V^Tfrag, P^Tfrag).
__global__ __launch_bounds__(64, 1) void attn_kernel(
    const unsigned short* __restrict__ Qh, const unsigned short* __restrict__ Kh,
    const unsigned short* __restrict__ Vt, unsigned short* __restrict__ Y) {
  const int l = threadIdx.x & 63;
  const int lo = l & 31, hi = l >> 5;
  const int bh = blockIdx.y;
  const int q0 = blockIdx.x * 64;
  const unsigned short* __restrict__ Kb = Kh + (size_t)bh * 2048 * 64;
  const unsigned short* __restrict__ Vb = Vt + (size_t)bh * 64 * 2048;
  const float cs = 0.125f * 1.44269504088896341f;  // 1/sqrt(64) * log2(e)

  // Q fragments (B-operand): lane holds Q[q0+s*32+lo][c*16+hi*8 ..+8]
  bf8v qf[2][4];
#pragma unroll
  for (int s = 0; s < 2; s++)
#pragma unroll
    for (int c = 0; c < 4; c++)
      qf[s][c] = *(const bf8v*)(Qh + (size_t)bh * 2048 * 64 +
                                (size_t)(q0 + s * 32 + lo) * 64 + c * 16 + hi * 8);

  f16v oacc[2][2];
#pragma unroll
  for (int s = 0; s < 2; s++)
#pragma unroll
    for (int dt = 0; dt < 2; dt++) oacc[s][dt] = (f16v)(0.0f);
  float mrun[2] = {-1e30f, -1e30f}, lrun[2] = {0.0f, 0.0f};

  // K-fragment (A-op): row kv=t+lo, k-elems c*16+hi*8 (c = K-step).
  // V^T-fragment (A-op): row d=dt*32+lo, k-elems (kv) kc*16+hi*8.
  auto LOADKV = [&](bf8v (&kf)[4], bf8v (&vf)[4], int t) {
#pragma unroll
    for (int c = 0; c < 4; c++)
      kf[c] = *(const bf8v*)(Kb + (size_t)(t + lo) * 64 + c * 16 + hi * 8);
#pragma unroll
    for (int dt = 0; dt < 2; dt++)
#pragma unroll
      for (int kc = 0; kc < 2; kc++)
        vf[dt * 2 + kc] = *(const bf8v*)(Vb + (size_t)(dt * 32 + lo) * 2048 +
                                         t + kc * 16 + hi * 8);
  };

  auto COMPUTE = [&](const bf8v (&kf)[4], const bf8v (&vf)[4]) {
    f16v sa = (f16v)(0.0f), sb = (f16v)(0.0f);
#pragma unroll
    for (int c = 0; c < 4; c++) {
      sa = __builtin_amdgcn_mfma_f32_32x32x16_bf16(kf[c], qf[0][c], sa, 0, 0, 0);
      sb = __builtin_amdgcn_mfma_f32_32x32x16_bf16(kf[c], qf[1][c], sb, 0, 0, 0);
    }
#pragma unroll
    for (int s = 0; s < 2; s++) {
      const f16v& sc16 = (s == 0) ? sa : sb;
      // row max: max3 tree over 16 + partner half
      float m0a = fmaxf(fmaxf(sc16[0], sc16[1]), sc16[2]);
      float m0b = fmaxf(fmaxf(sc16[3], sc16[4]), sc16[5]);
      float m0c = fmaxf(fmaxf(sc16[6], sc16[7]), sc16[8]);
      float m0d = fmaxf(fmaxf(sc16[9], sc16[10]), sc16[11]);
      float m0e = fmaxf(fmaxf(sc16[12], sc16[13]), sc16[14]);
      float m16 = fmaxf(fmaxf(fmaxf(m0a, m0b), fmaxf(m0c, m0d)), fmaxf(m0e, sc16[15]));
      m16 = fmaxf(m16, __shfl_xor(m16, 32));
      float msc = m16 * cs;
      if (!__all(msc <= mrun[s] + 8.0f)) {       // T13 defer-max
        float mnew = fmaxf(mrun[s], msc);
        float scl = __builtin_amdgcn_exp2f(mrun[s] - mnew);
        lrun[s] *= scl;
#pragma unroll
        for (int dt = 0; dt < 2; dt++)
#pragma unroll
          for (int r = 0; r < 16; r++) oacc[s][dt][r] *= scl;
        mrun[s] = mnew;
      }
      float p[16];
      float rs = 0.0f;
#pragma unroll
      for (int r = 0; r < 16; r++) {
        p[r] = __builtin_amdgcn_exp2f(sc16[r] * cs - mrun[s]);
        rs += p[r];
      }
      rs += __shfl_xor(rs, 32);
      lrun[s] += rs;
      // T12: pack to bf16 + permlane32_swap -> P^T B-operand fragments
      bf8v pf[2];
#pragma unroll
      for (int kc = 0; kc < 2; kc++) {
        unsigned a0 = cvtpk(p[kc * 8 + 0], p[kc * 8 + 1]);
        unsigned a1 = cvtpk(p[kc * 8 + 2], p[kc * 8 + 3]);
        unsigned b0 = cvtpk(p[kc * 8 + 4], p[kc * 8 + 5]);
        unsigned b1 = cvtpk(p[kc * 8 + 6], p[kc * 8 + 7]);
        asm("v_permlane32_swap_b32 %0, %1" : "+v"(a0), "+v"(b0));
        asm("v_permlane32_swap_b32 %0, %1" : "+v"(a1), "+v"(b1));
        u4v pw;
        pw[0] = a0; pw[1] = a1; pw[2] = b0; pw[3] = b1;
        pf[kc] = __builtin_bit_cast(bf8v, pw);
      }
#pragma unroll
      for (int dt = 0; dt < 2; dt++)
#pragma unroll
        for (int kc = 0; kc < 2; kc++)
          oacc[s][dt] = __builtin_amdgcn_mfma_f32_32x32x16_bf16(vf[dt * 2 + kc], pf[kc],
                                                               oacc[s][dt], 0, 0, 0);
    }
  };

  bf8v kA[4], vA[4], kB[4], vB[4];
  LOADKV(kA, vA, 0);
#pragma unroll 1
  for (int t = 0; t < 2048; t += 64) {
    LOADKV(kB, vB, t + 32);
    COMPUTE(kA, vA);
    if (t + 64 < 2048) LOADKV(kA, vA, t + 64);
    COMPUTE(kB, vB);
  }

  // epilogue: normalize, write Y (B,S,D) bf16. Lane holds O^T[d][q=lo].
  const int b = bh >> 4, h = bh & 15;
#pragma unroll
  for (int s = 0; s < 2; s++) {
    float inv = 1.0f / lrun[s];
    int q = q0 + s * 32 + lo;
    size_t base = ((size_t)(b * 2048 + q) << 10) + h * 64;
#pragma unroll
    for (int dt = 0; dt < 2; dt++)
#pragma unroll
      for (int r = 0; r < 16; r++) {
        int d = dt * 32 + (r & 3) + 8 * (r >> 2) + 4 * hi;
        Y[base + d] = f2bf(oacc[s][dt][r] * inv);
      }
  }
}

// ---------------- launch ----------------
extern "C" void kernel_launch(void* const* d_in, const int* in_sizes, int n_in,
                              void* d_out, int out_size, void* d_ws, size_t ws_size,
                              hipStream_t stream) {
  const float* q  = (const float*)d_in[0];
  const float* k  = (const float*)d_in[1];
  const float* v  = (const float*)d_in[2];
  const float* Wq = (const float*)d_in[3];
  const float* Wk = (const float*)d_in[4];
  const float* Wv = (const float*)d_in[5];
  const float* Wo = (const float*)d_in[6];
  const float* bq = (const float*)d_in[7];
  const float* bk = (const float*)d_in[8];
  const float* bv = (const float*)d_in[9];
  const float* bo = (const float*)d_in[10];

  const size_t NA = (size_t)4096 * 1024;
  const size_t NW = (size_t)1024 * 1024;
  unsigned short* qA  = (unsigned short*)d_ws;   // cvt dst: q,k,v,Wq,Wk,Wv,Wo contiguous
  unsigned short* kA  = qA  + NA;
  unsigned short* vA  = kA  + NA;
  unsigned short* WqB = vA  + NA;
  unsigned short* WkB = WqB + NW;
  unsigned short* WvB = WkB + NW;
  unsigned short* WoB = WvB + NW;
  unsigned short* Qh  = WoB + NW;
  unsigned short* Kh  = Qh  + NA;
  unsigned short* Vt  = Kh  + NA;
  unsigned short* Y   = Vt  + NA;

  cvt_all<<<dim3(8192), 256, 0, stream>>>(q, k, v, Wq, Wk, Wv, Wo, qA);

  qkv_gemm<<<dim3(32, 8, 3), 256, 0, stream>>>(qA, kA, vA, WqB, WkB, WvB,
                                               bq, bk, bv, Qh, Kh, Vt);
  attn_kernel<<<dim3(32, 32), 64, 0, stream>>>(Qh, Kh, Vt, Y);
  out_gemm<<<dim3(32, 8), 256, 0, stream>>>(Y, WoB, bo, (float*)d_out);
}

// Round 4
// 128.499 us; speedup vs baseline: 1.3143x; 1.3143x over previous
//
#include <hip/hip_runtime.h>
#include <stdint.h>

typedef __attribute__((ext_vector_type(8))) short bf8v;   // 8 bf16 raw bits (4 VGPRs)
typedef __attribute__((ext_vector_type(4))) float f4v;
typedef __attribute__((ext_vector_type(16))) float f16v;
typedef __attribute__((ext_vector_type(4))) unsigned int u4v;

__device__ __forceinline__ unsigned short f2bf(float f) {
  unsigned int u = __float_as_uint(f);
  u += 0x7fffu + ((u >> 16) & 1u);   // round-to-nearest-even
  return (unsigned short)(u >> 16);
}

__device__ __forceinline__ void gload16(const void* g, void* l) {
  __builtin_amdgcn_global_load_lds(
      (__attribute__((address_space(1))) void*)reinterpret_cast<uintptr_t>(g),
      (__attribute__((address_space(3))) void*)reinterpret_cast<uintptr_t>(l),
      16, 0, 0);
}

__device__ __forceinline__ unsigned cvtpk(float lo, float hi) {
  unsigned r;
  asm("v_cvt_pk_bf16_f32 %0, %1, %2" : "=v"(r) : "v"(lo), "v"(hi));
  return r;
}

// ---------------- fp32 -> bf16 conversion (single fused launch) ----------------
__global__ __launch_bounds__(256) void cvt_all(
    const float* __restrict__ s0, const float* __restrict__ s1,
    const float* __restrict__ s2, const float* __restrict__ s3,
    const float* __restrict__ s4, const float* __restrict__ s5,
    const float* __restrict__ s6, unsigned short* __restrict__ dst) {
  const size_t NA = (size_t)1 << 22, NW = (size_t)1 << 20;
  size_t i = ((size_t)blockIdx.x * 256 + threadIdx.x) * 8;
  const float* src;
  size_t off;
  if (i < 3 * NA) {
    int a = (int)(i >> 22);
    src = (a == 0) ? s0 : (a == 1) ? s1 : s2;
    off = i & (NA - 1);
  } else {
    size_t j = i - 3 * NA;
    int a = (int)(j >> 20);
    src = (a == 0) ? s3 : (a == 1) ? s4 : (a == 2) ? s5 : s6;
    off = j & (NW - 1);
  }
  const f4v* sp = (const f4v*)(src + off);
  f4v x = sp[0], y = sp[1];
  bf8v r;
  r[0] = (short)f2bf(x[0]); r[1] = (short)f2bf(x[1]);
  r[2] = (short)f2bf(x[2]); r[3] = (short)f2bf(x[3]);
  r[4] = (short)f2bf(y[0]); r[5] = (short)f2bf(y[1]);
  r[6] = (short)f2bf(y[2]); r[7] = (short)f2bf(y[3]);
  *(bf8v*)(dst + i) = r;
}

// ---------------- 128x128x(BK=32) bf16 GEMM body (m97 structure) ----------------
template <int OMODE>
__device__ __forceinline__ void gemm_body(
    unsigned short* Al, unsigned short* Bl,
    const unsigned short* __restrict__ A, const unsigned short* __restrict__ W,
    const float* __restrict__ bias, void* __restrict__ out) {
  const int tid = threadIdx.x;
  const int w = tid >> 6, l = tid & 63;
  const int lr = l >> 4, lc = l & 15;
  const int m0 = blockIdx.x * 128, n0 = blockIdx.y * 128;
  const int wr = w >> 1, wc = w & 1;

  f4v acc[4][4];
#pragma unroll
  for (int i = 0; i < 4; i++)
#pragma unroll
    for (int j = 0; j < 4; j++) acc[i][j] = (f4v)(0.0f);

  const int NK = 32;
#pragma unroll
  for (int i = 0; i < 2; i++) {
    int chunk = w * 2 + i;
    int e = (chunk * 1024 + l * 16) >> 1;
    int r = e >> 5, k = e & 31;
    gload16(A + (size_t)(m0 + r) * 1024 + k, Al + chunk * 512);
    gload16(W + (size_t)(n0 + r) * 1024 + k, Bl + chunk * 512);
  }

  for (int kk = 0; kk < NK; kk++) {
    const int cur = kk & 1;
    __syncthreads();
    if (kk + 1 < NK) {
#pragma unroll
      for (int i = 0; i < 2; i++) {
        int chunk = w * 2 + i;
        int e = (chunk * 1024 + l * 16) >> 1;
        int r = e >> 5, k = (kk + 1) * 32 + (e & 31);
        gload16(A + (size_t)(m0 + r) * 1024 + k, Al + (cur ^ 1) * 4096 + chunk * 512);
        gload16(W + (size_t)(n0 + r) * 1024 + k, Bl + (cur ^ 1) * 4096 + chunk * 512);
      }
    }
    bf8v av[4], bv[4];
#pragma unroll
    for (int i = 0; i < 4; i++) {
      int row = wr * 64 + i * 16 + lc;
      av[i] = *(const bf8v*)(Al + cur * 4096 + row * 32 + lr * 8);
    }
#pragma unroll
    for (int j = 0; j < 4; j++) {
      int row = wc * 64 + j * 16 + lc;
      bv[j] = *(const bf8v*)(Bl + cur * 4096 + row * 32 + lr * 8);
    }
#pragma unroll
    for (int i = 0; i < 4; i++)
#pragma unroll
      for (int j = 0; j < 4; j++)
        acc[i][j] = __builtin_amdgcn_mfma_f32_16x16x32_bf16(av[i], bv[j], acc[i][j], 0, 0, 0);
  }

#pragma unroll
  for (int j = 0; j < 4; j++) {
    int n = n0 + wc * 64 + j * 16 + lc;
    float bj = bias[n];
#pragma unroll
    for (int i = 0; i < 4; i++) {
      int mb = m0 + wr * 64 + i * 16 + lr * 4;
#pragma unroll
      for (int q = 0; q < 4; q++) {
        float val = fmaxf(acc[i][j][q] + bj, 0.0f);
        int m = mb + q;
        if (OMODE == 2) {
          int s = m & 2047, b = m >> 11;
          ((float*)out)[(size_t)(s * 2 + b) * 1024 + n] = val;
        } else {
          int s = m >> 1, b = m & 1;
          int h = n >> 6, d = n & 63;
          if (OMODE == 0)
            ((unsigned short*)out)[((size_t)(b * 16 + h) * 2048 + s) * 64 + d] = f2bf(val);
          else
            ((unsigned short*)out)[((size_t)(b * 16 + h) * 64 + d) * 2048 + s] = f2bf(val);
        }
      }
    }
  }
}

__global__ __launch_bounds__(256) void qkv_gemm(
    const unsigned short* __restrict__ qA, const unsigned short* __restrict__ kA,
    const unsigned short* __restrict__ vA,
    const unsigned short* __restrict__ Wq, const unsigned short* __restrict__ Wk,
    const unsigned short* __restrict__ Wv,
    const float* __restrict__ bq, const float* __restrict__ bk,
    const float* __restrict__ bv,
    unsigned short* __restrict__ Qh, unsigned short* __restrict__ Kh,
    unsigned short* __restrict__ Vt) {
  __shared__ __align__(16) unsigned short Al[2 * 4096];
  __shared__ __align__(16) unsigned short Bl[2 * 4096];
  int z = blockIdx.z;
  if (z == 0)      gemm_body<0>(Al, Bl, qA, Wq, bq, Qh);
  else if (z == 1) gemm_body<0>(Al, Bl, kA, Wk, bk, Kh);
  else             gemm_body<1>(Al, Bl, vA, Wv, bv, Vt);
}

__global__ __launch_bounds__(256) void out_gemm(
    const unsigned short* __restrict__ Y, const unsigned short* __restrict__ Wo,
    const float* __restrict__ bo, float* __restrict__ out) {
  __shared__ __align__(16) unsigned short Al[2 * 4096];
  __shared__ __align__(16) unsigned short Bl[2 * 4096];
  gemm_body<2>(Al, Bl, Y, Wo, bo, out);
}

// ---------------- flash attention, 32x32 swapped, LDS-staged, 4-wave ----------------
// Qh,Kh: (BH=32, S=2048, 64) bf16.  Vt: (BH, 64, S) bf16.  Y: (B,S,D) bf16.
// Grid (16, 32), 256 threads = 4 waves; wave w owns 32 q (q0 = bx*128+w*32).
// 2048 waves total -> 8 waves/CU = 2/SIMD (double round-2's TLP).
// Double-buffered LDS K[64][64]/V^T[64][64], XOR-swizzle ((row&7)<<4),
// staged via global_load_lds with pre-swizzled source (rule #21).
// QK^T: S^T[kv][q]=mfma(K,Q) -> lane holds 16 p for q=lane&31; softmax in-lane
// + shfl_xor(32); T12 cvt_pk+permlane32_swap; T13 defer-max;
// PV: O^T[d][q]=mfma(V^T,P^T).
__global__ __launch_bounds__(256, 2) void attn_kernel(
    const unsigned short* __restrict__ Qh, const unsigned short* __restrict__ Kh,
    const unsigned short* __restrict__ Vt, unsigned short* __restrict__ Y) {
  __shared__ __align__(16) unsigned short Kl[2][4096];
  __shared__ __align__(16) unsigned short Vl[2][4096];
  const int tid = threadIdx.x, w = tid >> 6, l = tid & 63;
  const int lo = l & 31, hi = l >> 5;
  const int bh = blockIdx.y;
  const int q0 = blockIdx.x * 128 + w * 32;
  const size_t qkbase = (size_t)bh * 2048 * 64;
  const size_t vtbase = (size_t)bh * 64 * 2048;
  const float cs = 0.125f * 1.44269504088896341f;  // 1/sqrt(64) * log2(e)

  // Q fragments (B-operand): lane holds Q[q0+lo][c*16+hi*8 ..+8]
  bf8v qf[4];
#pragma unroll
  for (int c = 0; c < 4; c++)
    qf[c] = *(const bf8v*)(Qh + qkbase + (size_t)(q0 + lo) * 64 + c * 16 + hi * 8);

  f16v oacc[2];
  oacc[0] = (f16v)(0.0f);
  oacc[1] = (f16v)(0.0f);
  float mrun = -1e30f, lrun = 0.0f;

  // LDS read byte-addresses (within one 8KB buffer), swizzle (lo&7)<<4
  const int swl = (lo & 7) << 4;
  int akb[4], avb[2][2][2];
#pragma unroll
  for (int c = 0; c < 4; c++) akb[c] = lo * 128 + ((c * 32 + hi * 16) ^ swl);
#pragma unroll
  for (int dt = 0; dt < 2; dt++)
#pragma unroll
    for (int kvh = 0; kvh < 2; kvh++)
#pragma unroll
      for (int kc = 0; kc < 2; kc++)
        avb[dt][kvh][kc] = (dt * 32 + lo) * 128 + ((kvh * 64 + kc * 32 + hi * 16) ^ swl);

  // staging source elements (pre-swizzled: linear LDS dest + swizzled read match)
  int stE[2], stD[2], stKV[2];
#pragma unroll
  for (int i = 0; i < 2; i++) {
    int o = (w * 2 + i) * 1024 + l * 16;
    int row = o >> 7;
    stE[i] = (o ^ ((row & 7) << 4)) >> 1;
    stD[i] = stE[i] >> 6;
    stKV[i] = stE[i] & 63;
  }
  const char* KlB = (const char*)&Kl[0][0];
  const char* VlB = (const char*)&Vl[0][0];

  auto STAGE = [&](int buf, int t0) {
#pragma unroll
    for (int i = 0; i < 2; i++) {
      gload16(Kh + qkbase + (size_t)t0 * 64 + stE[i], (char*)&Kl[buf][0] + (w * 2 + i) * 1024);
      gload16(Vt + vtbase + (size_t)stD[i] * 2048 + t0 + stKV[i], (char*)&Vl[buf][0] + (w * 2 + i) * 1024);
    }
  };

  auto COMPUTE = [&](int bo) {
#pragma unroll
    for (int kvh = 0; kvh < 2; kvh++) {
      // K fragments (A-operand): row kv = kvh*32+lo, k = d
      bf8v kf[4];
#pragma unroll
      for (int c = 0; c < 4; c++)
        kf[c] = *(const bf8v*)(KlB + bo + kvh * 4096 + akb[c]);
      f16v sc16 = (f16v)(0.0f);
#pragma unroll
      for (int c = 0; c < 4; c++)
        sc16 = __builtin_amdgcn_mfma_f32_32x32x16_bf16(kf[c], qf[c], sc16, 0, 0, 0);
      // V^T fragments (A-operand): row d = dt*32+lo, k = kv (issue early)
      bf8v vf[2][2];
#pragma unroll
      for (int dt = 0; dt < 2; dt++)
#pragma unroll
        for (int kc = 0; kc < 2; kc++)
          vf[dt][kc] = *(const bf8v*)(VlB + bo + avb[dt][kvh][kc]);

      // row max: max3-friendly tree over 16 in-lane + partner half
      float m0a = fmaxf(fmaxf(sc16[0], sc16[1]), sc16[2]);
      float m0b = fmaxf(fmaxf(sc16[3], sc16[4]), sc16[5]);
      float m0c = fmaxf(fmaxf(sc16[6], sc16[7]), sc16[8]);
      float m0d = fmaxf(fmaxf(sc16[9], sc16[10]), sc16[11]);
      float m0e = fmaxf(fmaxf(sc16[12], sc16[13]), sc16[14]);
      float m16 = fmaxf(fmaxf(fmaxf(m0a, m0b), fmaxf(m0c, m0d)), fmaxf(m0e, sc16[15]));
      m16 = fmaxf(m16, __shfl_xor(m16, 32));
      float msc = m16 * cs;
      if (!__all(msc <= mrun + 8.0f)) {          // T13 defer-max
        float mnew = fmaxf(mrun, msc);
        float scl = __builtin_amdgcn_exp2f(mrun - mnew);
        lrun *= scl;
#pragma unroll
        for (int dt = 0; dt < 2; dt++)
#pragma unroll
          for (int r = 0; r < 16; r++) oacc[dt][r] *= scl;
        mrun = mnew;
      }
      float p[16];
      float rs = 0.0f;
#pragma unroll
      for (int r = 0; r < 16; r++) {
        p[r] = __builtin_amdgcn_exp2f(sc16[r] * cs - mrun);
        rs += p[r];
      }
      rs += __shfl_xor(rs, 32);
      lrun += rs;
      // T12: pack to bf16 + permlane32_swap -> P^T B-operand fragments
      bf8v pf[2];
#pragma unroll
      for (int kc = 0; kc < 2; kc++) {
        unsigned a0 = cvtpk(p[kc * 8 + 0], p[kc * 8 + 1]);
        unsigned a1 = cvtpk(p[kc * 8 + 2], p[kc * 8 + 3]);
        unsigned b0 = cvtpk(p[kc * 8 + 4], p[kc * 8 + 5]);
        unsigned b1 = cvtpk(p[kc * 8 + 6], p[kc * 8 + 7]);
        asm("v_permlane32_swap_b32 %0, %1" : "+v"(a0), "+v"(b0));
        asm("v_permlane32_swap_b32 %0, %1" : "+v"(a1), "+v"(b1));
        u4v pw;
        pw[0] = a0; pw[1] = a1; pw[2] = b0; pw[3] = b1;
        pf[kc] = __builtin_bit_cast(bf8v, pw);
      }
#pragma unroll
      for (int dt = 0; dt < 2; dt++)
#pragma unroll
        for (int kc = 0; kc < 2; kc++)
          oacc[dt] = __builtin_amdgcn_mfma_f32_32x32x16_bf16(vf[dt][kc], pf[kc], oacc[dt], 0, 0, 0);
    }
  };

  STAGE(0, 0);
  __syncthreads();
#pragma unroll 1
  for (int t0 = 0; t0 < 2048; t0 += 128) {
    STAGE(1, t0 + 64);          // always valid: last staged tile is 1984
    COMPUTE(0);
    __syncthreads();
    if (t0 + 128 < 2048) STAGE(0, t0 + 128);
    COMPUTE(8192);
    __syncthreads();
  }

  // epilogue: normalize, write Y (B,S,D) bf16. Lane holds O^T[d][q=lo].
  const int b = bh >> 4, h = bh & 15;
  {
    float inv = 1.0f / lrun;
    int q = q0 + lo;
    size_t base = ((size_t)(b * 2048 + q) << 10) + h * 64;
#pragma unroll
    for (int dt = 0; dt < 2; dt++)
#pragma unroll
      for (int r = 0; r < 16; r++) {
        int d = dt * 32 + (r & 3) + 8 * (r >> 2) + 4 * hi;
        Y[base + d] = f2bf(oacc[dt][r] * inv);
      }
  }
}

// ---------------- launch ----------------
extern "C" void kernel_launch(void* const* d_in, const int* in_sizes, int n_in,
                              void* d_out, int out_size, void* d_ws, size_t ws_size,
                              hipStream_t stream) {
  const float* q  = (const float*)d_in[0];
  const float* k  = (const float*)d_in[1];
  const float* v  = (const float*)d_in[2];
  const float* Wq = (const float*)d_in[3];
  const float* Wk = (const float*)d_in[4];
  const float* Wv = (const float*)d_in[5];
  const float* Wo = (const float*)d_in[6];
  const float* bq = (const float*)d_in[7];
  const float* bk = (const float*)d_in[8];
  const float* bv = (const float*)d_in[9];
  const float* bo = (const float*)d_in[10];

  const size_t NA = (size_t)4096 * 1024;
  const size_t NW = (size_t)1024 * 1024;
  unsigned short* qA  = (unsigned short*)d_ws;   // cvt dst: q,k,v,Wq,Wk,Wv,Wo contiguous
  unsigned short* kA  = qA  + NA;
  unsigned short* vA  = kA  + NA;
  unsigned short* WqB = vA  + NA;
  unsigned short* WkB = WqB + NW;
  unsigned short* WvB = WkB + NW;
  unsigned short* WoB = WvB + NW;
  unsigned short* Qh  = WoB + NW;
  unsigned short* Kh  = Qh  + NA;
  unsigned short* Vt  = Kh  + NA;
  unsigned short* Y   = Vt  + NA;

  cvt_all<<<dim3(8192), 256, 0, stream>>>(q, k, v, Wq, Wk, Wv, Wo, qA);

  qkv_gemm<<<dim3(32, 8, 3), 256, 0, stream>>>(qA, kA, vA, WqB, WkB, WvB,
                                               bq, bk, bv, Qh, Kh, Vt);
  attn_kernel<<<dim3(16, 32), 256, 0, stream>>>(Qh, Kh, Vt, Y);
  out_gemm<<<dim3(32, 8), 256, 0, stream>>>(Y, WoB, bo, (float*)d_out);
}